// Round 2
// baseline (517.115 us; speedup 1.0000x reference)
//
#include <hip/hip_runtime.h>
#include <stdint.h>

#define TT 2048
#define HH 1024
#define II 4096
#define EE 8

typedef __attribute__((ext_vector_type(4))) float floatx4;
typedef __attribute__((ext_vector_type(8))) __bf16 bf16x8;

// round-to-nearest-even fp32 -> bf16 (bits)
__device__ __forceinline__ unsigned short f2bf(float f) {
  union { float f; unsigned u; } v; v.f = f;
  return (unsigned short)((v.u + 0x7FFFu + ((v.u >> 16) & 1u)) >> 16);
}

// async global->LDS, 16 bytes per lane; LDS dest must be wave-uniform base + lane*16
__device__ __forceinline__ void async_ld16(const void* g, void* l) {
  __builtin_amdgcn_global_load_lds(
      (__attribute__((address_space(1))) void*)g,
      (__attribute__((address_space(3))) void*)l, 16, 0, 0);
}

// ---------------- gating: fp32 logits, softmax top-2, renorm; emit x_bf16 ----
__global__ __launch_bounds__(256) void k_gating(
    const float* __restrict__ x, const float* __restrict__ gw,
    unsigned short* __restrict__ xb, int* __restrict__ sel_e,
    float* __restrict__ sel_w, int* __restrict__ counts) {
  int t = blockIdx.x;
  int tid = threadIdx.x;
  floatx4 xv = ((const floatx4*)(x + (size_t)t * HH))[tid];
  ushort4 xo;
  xo.x = f2bf(xv.x); xo.y = f2bf(xv.y); xo.z = f2bf(xv.z); xo.w = f2bf(xv.w);
  ((ushort4*)(xb + (size_t)t * HH))[tid] = xo;

  float part[EE];
#pragma unroll
  for (int e = 0; e < EE; e++) {
    floatx4 g = ((const floatx4*)(gw + e * HH))[tid];
    part[e] = xv.x * g.x + xv.y * g.y + xv.z * g.z + xv.w * g.w;
  }
#pragma unroll
  for (int e = 0; e < EE; e++) {
    float v = part[e];
#pragma unroll
    for (int off = 32; off > 0; off >>= 1) v += __shfl_down(v, off, 64);
    part[e] = v;
  }
  __shared__ float red[4][EE];
  int wave = tid >> 6;
  if ((tid & 63) == 0) {
#pragma unroll
    for (int e = 0; e < EE; e++) red[wave][e] = part[e];
  }
  __syncthreads();
  if (tid == 0) {
    float lg[EE];
#pragma unroll
    for (int e = 0; e < EE; e++)
      lg[e] = red[0][e] + red[1][e] + red[2][e] + red[3][e];
    int e0 = 0;
#pragma unroll
    for (int e = 1; e < EE; e++) if (lg[e] > lg[e0]) e0 = e;
    int e1 = (e0 == 0) ? 1 : 0;
#pragma unroll
    for (int e = 0; e < EE; e++) if (e != e0 && lg[e] > lg[e1]) e1 = e;
    float w0 = 1.f / (1.f + expf(lg[e1] - lg[e0]));
    sel_e[t * 2] = e0; sel_e[t * 2 + 1] = e1;
    sel_w[t * 2] = w0; sel_w[t * 2 + 1] = 1.f - w0;
    atomicAdd(&counts[e0], 1);
    atomicAdd(&counts[e1], 1);
  }
}

// ---------------- scan + fill (single block, LDS counters) ------------------
__global__ __launch_bounds__(256) void k_fill(
    const int* __restrict__ counts, const int* __restrict__ sel_e,
    const float* __restrict__ sel_w, int* __restrict__ bases,
    int* __restrict__ row_token, float* __restrict__ row_w,
    int* __restrict__ inv_slot) {
  __shared__ int lb[EE];
  __shared__ int lc[EE];
  int tid = threadIdx.x;
  if (tid == 0) {
    int s = 0;
    for (int e = 0; e < EE; e++) { lb[e] = s; s += counts[e]; }
  }
  if (tid < EE) lc[tid] = 0;
  __syncthreads();
  for (int p = tid; p < TT * 2; p += 256) {
    int e = sel_e[p];
    int slot = lb[e] + atomicAdd(&lc[e], 1);
    row_token[slot] = p >> 1;
    row_w[slot] = sel_w[p];
    inv_slot[p] = slot;
  }
  __syncthreads();
  if (tid < EE) bases[tid] = lb[tid];
}

// ---------------- weight conversion fp32 -> bf16 (branchless, no loop) ------
// grid = 2 * (E*I*H / (256*8)); first half does w1, second half w2.
__global__ __launch_bounds__(256) void k_convert(
    const float* __restrict__ w1, const float* __restrict__ w2,
    unsigned short* __restrict__ w1b, unsigned short* __restrict__ w2b) {
  const int half_blocks = (int)(((size_t)EE * II * HH) / (256 * 8));
  const float* s;
  unsigned short* d;
  int b = blockIdx.x;
  if (b < half_blocks) { s = w1; d = w1b; } else { s = w2; d = w2b; b -= half_blocks; }
  size_t i = ((size_t)b * 256 + threadIdx.x) * 8;
  floatx4 v0 = *(const floatx4*)(s + i);
  floatx4 v1 = *(const floatx4*)(s + i + 4);
  uint4 o;
  o.x = (unsigned)f2bf(v0.x) | ((unsigned)f2bf(v0.y) << 16);
  o.y = (unsigned)f2bf(v0.z) | ((unsigned)f2bf(v0.w) << 16);
  o.z = (unsigned)f2bf(v1.x) | ((unsigned)f2bf(v1.y) << 16);
  o.w = (unsigned)f2bf(v1.z) | ((unsigned)f2bf(v1.w) << 16);
  *(uint4*)(d + i) = o;
}

// ---------------- GEMM1: hid = silu(x @ w1^T), per-expert gathered rows -----
__global__ __launch_bounds__(256, 3) void k_gemm1(
    const unsigned short* __restrict__ xb,
    const unsigned short* __restrict__ w1b,
    unsigned short* __restrict__ hid,
    const int* __restrict__ counts, const int* __restrict__ bases,
    const int* __restrict__ row_token) {
  const int e = blockIdx.z;
  const int count = counts[e];
  const int m0 = blockIdx.y * 128;
  if (m0 >= count) return;
  const int n0 = blockIdx.x * 128;
  const int base = bases[e];

  __shared__ __align__(16) unsigned short Smem[128 * 32 * 2];  // 16 KB
  unsigned short* As = Smem;
  unsigned short* Bs = Smem + 128 * 32;

  const int tid = threadIdx.x;
  const int lane = tid & 63;
  const int wave = tid >> 6;
  const int wm = (wave & 1) * 64;
  const int wn = (wave >> 1) * 64;
  const int quad = lane >> 4;
  const int l16 = lane & 15;

  const int rA0 = tid >> 2;       // rows 0..63
  const int rA1 = rA0 + 64;       // rows 64..127
  const int cc = (tid & 3) * 8;   // element col offset (8 bf16 = 16B chunk)

  int g0 = m0 + rA0; if (g0 > count - 1) g0 = count - 1;
  int g1 = m0 + rA1; if (g1 > count - 1) g1 = count - 1;
  const unsigned short* aS0 = xb + (size_t)row_token[base + g0] * HH + cc;
  const unsigned short* aS1 = xb + (size_t)row_token[base + g1] * HH + cc;
  const unsigned short* wp = w1b + (size_t)e * II * HH;
  const unsigned short* bS0 = wp + (size_t)(n0 + rA0) * HH + cc;
  const unsigned short* bS1 = wp + (size_t)(n0 + rA1) * HH + cc;

  unsigned short* lA0 = As + tid * 8;
  unsigned short* lA1 = As + tid * 8 + 2048;
  unsigned short* lB0 = Bs + tid * 8;
  unsigned short* lB1 = Bs + tid * 8 + 2048;

  const floatx4 fz = {0.f, 0.f, 0.f, 0.f};
  floatx4 acc[4][4];
#pragma unroll
  for (int i = 0; i < 4; i++)
#pragma unroll
    for (int j = 0; j < 4; j++) acc[i][j] = fz;

  for (int k0 = 0; k0 < HH; k0 += 32) {
    async_ld16(aS0 + k0, lA0);
    async_ld16(aS1 + k0, lA1);
    async_ld16(bS0 + k0, lB0);
    async_ld16(bS1 + k0, lB1);
    __syncthreads();
    bf16x8 af[4], bfr[4];
#pragma unroll
    for (int i = 0; i < 4; i++) {
      af[i]  = *(const bf16x8*)(As + (wm + i * 16 + l16) * 32 + quad * 8);
      bfr[i] = *(const bf16x8*)(Bs + (wn + i * 16 + l16) * 32 + quad * 8);
    }
#pragma unroll
    for (int i = 0; i < 4; i++)
#pragma unroll
      for (int j = 0; j < 4; j++)
        acc[i][j] = __builtin_amdgcn_mfma_f32_16x16x32_bf16(af[i], bfr[j], acc[i][j], 0, 0, 0);
    __syncthreads();
  }

  // epilogue: silu -> bf16 -> per-wave LDS bounce -> coalesced 16B stores.
  // slice: 16 rows x 64 cols, padded row stride 72 ushorts (144 B, 16B-mult).
  unsigned short* Sl = Smem + wave * (16 * 72);
#pragma unroll
  for (int i = 0; i < 4; i++) {
#pragma unroll
    for (int r = 0; r < 4; r++) {
      const int row16 = quad * 4 + r;
#pragma unroll
      for (int j = 0; j < 4; j++) {
        float z = acc[i][j][r];
        Sl[row16 * 72 + l16 + 16 * j] = f2bf(z / (1.f + __expf(-z)));
      }
    }
#pragma unroll
    for (int half = 0; half < 2; half++) {
      const int row16 = (lane >> 3) + 8 * half;
      const int m = wm + i * 16 + row16;
      if (m0 + m < count) {
        bf16x8 v = *(const bf16x8*)(Sl + row16 * 72 + (lane & 7) * 8);
        *(bf16x8*)(hid + (size_t)(base + m0 + m) * II + n0 + wn + (lane & 7) * 8) = v;
      }
    }
  }
}

// ---------------- GEMM2: yp[ks][slot] = hid @ w2^T (split-K=2, plain stores)-
__global__ __launch_bounds__(256, 3) void k_gemm2(
    const unsigned short* __restrict__ hid,
    const unsigned short* __restrict__ w2b,
    float* __restrict__ yp,
    const int* __restrict__ counts, const int* __restrict__ bases) {
  const int e = blockIdx.z;
  const int count = counts[e];
  const int m0 = blockIdx.y * 128;
  if (m0 >= count) return;
  const int nt = blockIdx.x & 7;
  const int ks = blockIdx.x >> 3;
  const int n0 = nt * 128;
  const int base = bases[e];

  __shared__ __align__(16) unsigned short Smem2[128 * 32 * 2];
  unsigned short* As = Smem2;
  unsigned short* Bs = Smem2 + 128 * 32;

  const int tid = threadIdx.x;
  const int lane = tid & 63;
  const int wave = tid >> 6;
  const int wm = (wave & 1) * 64;
  const int wn = (wave >> 1) * 64;
  const int quad = lane >> 4;
  const int l16 = lane & 15;

  const int rA0 = tid >> 2;
  const int rA1 = rA0 + 64;
  const int cc = (tid & 3) * 8;

  int g0 = m0 + rA0; if (g0 > count - 1) g0 = count - 1;
  int g1 = m0 + rA1; if (g1 > count - 1) g1 = count - 1;
  const unsigned short* aS0 = hid + (size_t)(base + g0) * II + cc;
  const unsigned short* aS1 = hid + (size_t)(base + g1) * II + cc;
  const unsigned short* wp = w2b + (size_t)e * HH * II;
  const unsigned short* bS0 = wp + (size_t)(n0 + rA0) * II + cc;
  const unsigned short* bS1 = wp + (size_t)(n0 + rA1) * II + cc;

  unsigned short* lA0 = As + tid * 8;
  unsigned short* lA1 = As + tid * 8 + 2048;
  unsigned short* lB0 = Bs + tid * 8;
  unsigned short* lB1 = Bs + tid * 8 + 2048;

  const floatx4 fz = {0.f, 0.f, 0.f, 0.f};
  floatx4 acc[4][4];
#pragma unroll
  for (int i = 0; i < 4; i++)
#pragma unroll
    for (int j = 0; j < 4; j++) acc[i][j] = fz;

  const int kbeg = ks * (II / 2);
  const int kend = kbeg + II / 2;
  for (int k0 = kbeg; k0 < kend; k0 += 32) {
    async_ld16(aS0 + k0, lA0);
    async_ld16(aS1 + k0, lA1);
    async_ld16(bS0 + k0, lB0);
    async_ld16(bS1 + k0, lB1);
    __syncthreads();
    bf16x8 af[4], bfr[4];
#pragma unroll
    for (int i = 0; i < 4; i++) {
      af[i]  = *(const bf16x8*)(As + (wm + i * 16 + l16) * 32 + quad * 8);
      bfr[i] = *(const bf16x8*)(Bs + (wn + i * 16 + l16) * 32 + quad * 8);
    }
#pragma unroll
    for (int i = 0; i < 4; i++)
#pragma unroll
      for (int j = 0; j < 4; j++)
        acc[i][j] = __builtin_amdgcn_mfma_f32_16x16x32_bf16(af[i], bfr[j], acc[i][j], 0, 0, 0);
    __syncthreads();
  }

#pragma unroll
  for (int i = 0; i < 4; i++) {
#pragma unroll
    for (int r = 0; r < 4; r++) {
      const int m = wm + i * 16 + quad * 4 + r;
      if (m0 + m < count) {
        float* op = yp + ((size_t)ks * (TT * 2) + base + m0 + m) * HH + n0 + wn + l16;
#pragma unroll
        for (int j = 0; j < 4; j++) op[j * 16] = acc[i][j][r];
      }
    }
  }
}

// ---------------- combine: out[t] = sum_k w_k * (yp0[slot_k] + yp1[slot_k]) -
__global__ __launch_bounds__(256) void k_combine(
    const float* __restrict__ yp, const int* __restrict__ inv_slot,
    const float* __restrict__ sel_w, float* __restrict__ out) {
  const int t = blockIdx.x;
  const int tid = threadIdx.x;
  const int s0 = inv_slot[2 * t];
  const int s1 = inv_slot[2 * t + 1];
  const float w0 = sel_w[2 * t];
  const float w1 = sel_w[2 * t + 1];
  const floatx4 a0 = ((const floatx4*)(yp + (size_t)s0 * HH))[tid];
  const floatx4 a1 = ((const floatx4*)(yp + ((size_t)(TT * 2) + s0) * HH))[tid];
  const floatx4 b0 = ((const floatx4*)(yp + (size_t)s1 * HH))[tid];
  const floatx4 b1 = ((const floatx4*)(yp + ((size_t)(TT * 2) + s1) * HH))[tid];
  floatx4 v = w0 * (a0 + a1) + w1 * (b0 + b1);
  ((floatx4*)(out + (size_t)t * HH))[tid] = v;
}

// ---------------- launch ----------------------------------------------------
extern "C" void kernel_launch(void* const* d_in, const int* in_sizes, int n_in,
                              void* d_out, int out_size, void* d_ws, size_t ws_size,
                              hipStream_t stream) {
  const float* x  = (const float*)d_in[0];
  const float* gw = (const float*)d_in[1];
  const float* w1 = (const float*)d_in[2];
  const float* w2 = (const float*)d_in[3];
  float* out = (float*)d_out;

  char* ws = (char*)d_ws;
  size_t off = 0;
  auto take = [&](size_t n) -> char* {
    char* p = ws + off;
    off += (n + 255) & ~(size_t)255;
    return p;
  };
  unsigned short* xb  = (unsigned short*)take((size_t)TT * HH * 2);
  unsigned short* w1b = (unsigned short*)take((size_t)EE * II * HH * 2);
  unsigned short* w2b = (unsigned short*)take((size_t)EE * HH * II * 2);
  unsigned short* hid = (unsigned short*)take((size_t)TT * 2 * II * 2);
  int*   counts    = (int*)take(EE * 4);
  int*   bases     = (int*)take(EE * 4);
  int*   row_token = (int*)take((size_t)TT * 2 * 4);
  float* row_w     = (float*)take((size_t)TT * 2 * 4);
  int*   sel_e     = (int*)take((size_t)TT * 2 * 4);
  float* sel_w     = (float*)take((size_t)TT * 2 * 4);
  int*   inv_slot  = (int*)take((size_t)TT * 2 * 4);
  if (off > ws_size) return;  // workspace too small — fail loudly via absmax

  // y partials (2 splits x 4096 slots x 1024 fp32 = 33.5 MB) alias dead w1b (67 MB):
  // w1b is only read by k_gemm1, which completes before k_gemm2 writes yp.
  float* yp = (float*)w1b;

  hipMemsetAsync(counts, 0, EE * 4, stream);

  k_gating<<<TT, 256, 0, stream>>>(x, gw, xb, sel_e, sel_w, counts);
  k_fill<<<1, 256, 0, stream>>>(counts, sel_e, sel_w, bases, row_token, row_w, inv_slot);
  {
    const int half_blocks = (int)(((size_t)EE * II * HH) / (256 * 8));  // 16384
    k_convert<<<2 * half_blocks, 256, 0, stream>>>(w1, w2, w1b, w2b);
  }
  k_gemm1<<<dim3(II / 128, 16, EE), 256, 0, stream>>>(xb, w1b, hid, counts, bases, row_token);
  k_gemm2<<<dim3(16, 16, EE), 256, 0, stream>>>(hid, w2b, yp, counts, bases);
  k_combine<<<TT, 256, 0, stream>>>(yp, inv_slot, sel_w, out);
}

// Round 3
// 468.884 us; speedup vs baseline: 1.1029x; 1.1029x over previous
//
#include <hip/hip_runtime.h>
#include <stdint.h>

#define TT 2048
#define HH 1024
#define II 4096
#define EE 8
#define KS 4  // split-K factor for gemm2

typedef __attribute__((ext_vector_type(4))) float floatx4;
typedef __attribute__((ext_vector_type(8))) __bf16 bf16x8;

// round-to-nearest-even fp32 -> bf16 (bits)
__device__ __forceinline__ unsigned short f2bf(float f) {
  union { float f; unsigned u; } v; v.f = f;
  return (unsigned short)((v.u + 0x7FFFu + ((v.u >> 16) & 1u)) >> 16);
}

// async global->LDS, 16 bytes per lane; LDS dest must be wave-uniform base + lane*16
__device__ __forceinline__ void async_ld16(const void* g, void* l) {
  __builtin_amdgcn_global_load_lds(
      (__attribute__((address_space(1))) void*)g,
      (__attribute__((address_space(3))) void*)l, 16, 0, 0);
}

// ---------------- gating: fp32 logits, softmax top-2, renorm; emit x_bf16 ----
__global__ __launch_bounds__(256) void k_gating(
    const float* __restrict__ x, const float* __restrict__ gw,
    unsigned short* __restrict__ xb, int* __restrict__ sel_e,
    float* __restrict__ sel_w, int* __restrict__ counts) {
  int t = blockIdx.x;
  int tid = threadIdx.x;
  floatx4 xv = ((const floatx4*)(x + (size_t)t * HH))[tid];
  ushort4 xo;
  xo.x = f2bf(xv.x); xo.y = f2bf(xv.y); xo.z = f2bf(xv.z); xo.w = f2bf(xv.w);
  ((ushort4*)(xb + (size_t)t * HH))[tid] = xo;

  float part[EE];
#pragma unroll
  for (int e = 0; e < EE; e++) {
    floatx4 g = ((const floatx4*)(gw + e * HH))[tid];
    part[e] = xv.x * g.x + xv.y * g.y + xv.z * g.z + xv.w * g.w;
  }
#pragma unroll
  for (int e = 0; e < EE; e++) {
    float v = part[e];
#pragma unroll
    for (int off = 32; off > 0; off >>= 1) v += __shfl_down(v, off, 64);
    part[e] = v;
  }
  __shared__ float red[4][EE];
  int wave = tid >> 6;
  if ((tid & 63) == 0) {
#pragma unroll
    for (int e = 0; e < EE; e++) red[wave][e] = part[e];
  }
  __syncthreads();
  if (tid == 0) {
    float lg[EE];
#pragma unroll
    for (int e = 0; e < EE; e++)
      lg[e] = red[0][e] + red[1][e] + red[2][e] + red[3][e];
    int e0 = 0;
#pragma unroll
    for (int e = 1; e < EE; e++) if (lg[e] > lg[e0]) e0 = e;
    int e1 = (e0 == 0) ? 1 : 0;
#pragma unroll
    for (int e = 0; e < EE; e++) if (e != e0 && lg[e] > lg[e1]) e1 = e;
    float w0 = 1.f / (1.f + expf(lg[e1] - lg[e0]));
    sel_e[t * 2] = e0; sel_e[t * 2 + 1] = e1;
    sel_w[t * 2] = w0; sel_w[t * 2 + 1] = 1.f - w0;
    atomicAdd(&counts[e0], 1);
    atomicAdd(&counts[e1], 1);
  }
}

// ---------------- scan + fill (single block, LDS counters) ------------------
__global__ __launch_bounds__(256) void k_fill(
    const int* __restrict__ counts, const int* __restrict__ sel_e,
    const float* __restrict__ sel_w, int* __restrict__ bases,
    int* __restrict__ row_token, float* __restrict__ row_w,
    int* __restrict__ inv_slot) {
  __shared__ int lb[EE];
  __shared__ int lc[EE];
  int tid = threadIdx.x;
  if (tid == 0) {
    int s = 0;
    for (int e = 0; e < EE; e++) { lb[e] = s; s += counts[e]; }
  }
  if (tid < EE) lc[tid] = 0;
  __syncthreads();
  for (int p = tid; p < TT * 2; p += 256) {
    int e = sel_e[p];
    int slot = lb[e] + atomicAdd(&lc[e], 1);
    row_token[slot] = p >> 1;
    row_w[slot] = sel_w[p];
    inv_slot[p] = slot;
  }
  __syncthreads();
  if (tid < EE) bases[tid] = lb[tid];
}

// ---------------- GEMM1: hid = silu(x @ w1^T), fused fp32->bf16 B staging ---
__global__ __launch_bounds__(256) void k_gemm1(
    const unsigned short* __restrict__ xb,
    const float* __restrict__ w1,
    unsigned short* __restrict__ hid,
    const int* __restrict__ counts, const int* __restrict__ bases,
    const int* __restrict__ row_token) {
  const int e = blockIdx.z;
  const int count = counts[e];
  const int m0 = blockIdx.y * 128;
  if (m0 >= count) return;
  const int n0 = blockIdx.x * 128;
  const int base = bases[e];

  __shared__ __align__(16) unsigned short Smem[128 * 32 * 2];  // 16 KB
  unsigned short* As = Smem;
  unsigned short* Bs = Smem + 128 * 32;

  const int tid = threadIdx.x;
  const int lane = tid & 63;
  const int wave = tid >> 6;
  const int wm = (wave & 1) * 64;
  const int wn = (wave >> 1) * 64;
  const int quad = lane >> 4;
  const int l16 = lane & 15;

  const int rA0 = tid >> 2;       // rows 0..63
  const int rA1 = rA0 + 64;       // rows 64..127
  const int cc = (tid & 3) * 8;   // element col offset (8 elems = 16B bf16 / 32B fp32)

  int g0 = m0 + rA0; if (g0 > count - 1) g0 = count - 1;
  int g1 = m0 + rA1; if (g1 > count - 1) g1 = count - 1;
  const unsigned short* aS0 = xb + (size_t)row_token[base + g0] * HH + cc;
  const unsigned short* aS1 = xb + (size_t)row_token[base + g1] * HH + cc;
  const float* wp = w1 + (size_t)e * II * HH;
  const float* bp0 = wp + (size_t)(n0 + rA0) * HH + cc;
  const float* bp1 = wp + (size_t)(n0 + rA1) * HH + cc;

  unsigned short* lA0 = As + tid * 8;
  unsigned short* lA1 = As + tid * 8 + 2048;
  unsigned short* lB0 = Bs + tid * 8;
  unsigned short* lB1 = Bs + tid * 8 + 2048;

  const floatx4 fz = {0.f, 0.f, 0.f, 0.f};
  floatx4 acc[4][4];
#pragma unroll
  for (int i = 0; i < 4; i++)
#pragma unroll
    for (int j = 0; j < 4; j++) acc[i][j] = fz;

  // prefetch first B tile (fp32) into regs
  floatx4 f0a = *(const floatx4*)(bp0);
  floatx4 f0b = *(const floatx4*)(bp0 + 4);
  floatx4 f1a = *(const floatx4*)(bp1);
  floatx4 f1b = *(const floatx4*)(bp1 + 4);

  for (int k0 = 0; k0 < HH; k0 += 32) {
    // convert current B regs -> bf16, store to LDS
    bf16x8 wv0, wv1;
#pragma unroll
    for (int j = 0; j < 4; j++) {
      wv0[j] = (__bf16)f0a[j]; wv0[j + 4] = (__bf16)f0b[j];
      wv1[j] = (__bf16)f1a[j]; wv1[j + 4] = (__bf16)f1b[j];
    }
    *(bf16x8*)lB0 = wv0;
    *(bf16x8*)lB1 = wv1;
    async_ld16(aS0 + k0, lA0);
    async_ld16(aS1 + k0, lA1);
    __syncthreads();
    // prefetch next B tile — latency hides under MFMA below
    if (k0 + 32 < HH) {
      f0a = *(const floatx4*)(bp0 + k0 + 32);
      f0b = *(const floatx4*)(bp0 + k0 + 36);
      f1a = *(const floatx4*)(bp1 + k0 + 32);
      f1b = *(const floatx4*)(bp1 + k0 + 36);
    }
    bf16x8 af[4], bfr[4];
#pragma unroll
    for (int i = 0; i < 4; i++) {
      af[i]  = *(const bf16x8*)(As + (wm + i * 16 + l16) * 32 + quad * 8);
      bfr[i] = *(const bf16x8*)(Bs + (wn + i * 16 + l16) * 32 + quad * 8);
    }
#pragma unroll
    for (int i = 0; i < 4; i++)
#pragma unroll
      for (int j = 0; j < 4; j++)
        acc[i][j] = __builtin_amdgcn_mfma_f32_16x16x32_bf16(af[i], bfr[j], acc[i][j], 0, 0, 0);
    __syncthreads();
  }

  // epilogue: silu -> bf16 -> per-wave LDS bounce -> coalesced 16B stores.
  unsigned short* Sl = Smem + wave * (16 * 72);
#pragma unroll
  for (int i = 0; i < 4; i++) {
#pragma unroll
    for (int r = 0; r < 4; r++) {
      const int row16 = quad * 4 + r;
#pragma unroll
      for (int j = 0; j < 4; j++) {
        float z = acc[i][j][r];
        Sl[row16 * 72 + l16 + 16 * j] = f2bf(z / (1.f + __expf(-z)));
      }
    }
#pragma unroll
    for (int half = 0; half < 2; half++) {
      const int row16 = (lane >> 3) + 8 * half;
      const int m = wm + i * 16 + row16;
      if (m0 + m < count) {
        bf16x8 v = *(const bf16x8*)(Sl + row16 * 72 + (lane & 7) * 8);
        *(bf16x8*)(hid + (size_t)(base + m0 + m) * II + n0 + wn + (lane & 7) * 8) = v;
      }
    }
  }
}

// ---------------- GEMM2: yp[ks][slot] = hid @ w2^T, fused B conversion ------
__global__ __launch_bounds__(256) void k_gemm2(
    const unsigned short* __restrict__ hid,
    const float* __restrict__ w2,
    float* __restrict__ yp,
    const int* __restrict__ counts, const int* __restrict__ bases) {
  const int e = blockIdx.z;
  const int count = counts[e];
  const int m0 = blockIdx.y * 128;
  if (m0 >= count) return;
  const int nt = blockIdx.x & 7;
  const int ks = blockIdx.x >> 3;
  const int n0 = nt * 128;
  const int base = bases[e];

  __shared__ __align__(16) unsigned short Smem2[128 * 32 * 2];
  unsigned short* As = Smem2;
  unsigned short* Bs = Smem2 + 128 * 32;

  const int tid = threadIdx.x;
  const int lane = tid & 63;
  const int wave = tid >> 6;
  const int wm = (wave & 1) * 64;
  const int wn = (wave >> 1) * 64;
  const int quad = lane >> 4;
  const int l16 = lane & 15;

  const int rA0 = tid >> 2;
  const int rA1 = rA0 + 64;
  const int cc = (tid & 3) * 8;

  int g0 = m0 + rA0; if (g0 > count - 1) g0 = count - 1;
  int g1 = m0 + rA1; if (g1 > count - 1) g1 = count - 1;
  const unsigned short* aS0 = hid + (size_t)(base + g0) * II + cc;
  const unsigned short* aS1 = hid + (size_t)(base + g1) * II + cc;
  const float* wp = w2 + (size_t)e * HH * II;
  const float* bp0 = wp + (size_t)(n0 + rA0) * II + cc;
  const float* bp1 = wp + (size_t)(n0 + rA1) * II + cc;

  unsigned short* lA0 = As + tid * 8;
  unsigned short* lA1 = As + tid * 8 + 2048;
  unsigned short* lB0 = Bs + tid * 8;
  unsigned short* lB1 = Bs + tid * 8 + 2048;

  const floatx4 fz = {0.f, 0.f, 0.f, 0.f};
  floatx4 acc[4][4];
#pragma unroll
  for (int i = 0; i < 4; i++)
#pragma unroll
    for (int j = 0; j < 4; j++) acc[i][j] = fz;

  const int kbeg = ks * (II / KS);
  const int kend = kbeg + II / KS;

  floatx4 f0a = *(const floatx4*)(bp0 + kbeg);
  floatx4 f0b = *(const floatx4*)(bp0 + kbeg + 4);
  floatx4 f1a = *(const floatx4*)(bp1 + kbeg);
  floatx4 f1b = *(const floatx4*)(bp1 + kbeg + 4);

  for (int k0 = kbeg; k0 < kend; k0 += 32) {
    bf16x8 wv0, wv1;
#pragma unroll
    for (int j = 0; j < 4; j++) {
      wv0[j] = (__bf16)f0a[j]; wv0[j + 4] = (__bf16)f0b[j];
      wv1[j] = (__bf16)f1a[j]; wv1[j + 4] = (__bf16)f1b[j];
    }
    *(bf16x8*)lB0 = wv0;
    *(bf16x8*)lB1 = wv1;
    async_ld16(aS0 + k0, lA0);
    async_ld16(aS1 + k0, lA1);
    __syncthreads();
    if (k0 + 32 < kend) {
      f0a = *(const floatx4*)(bp0 + k0 + 32);
      f0b = *(const floatx4*)(bp0 + k0 + 36);
      f1a = *(const floatx4*)(bp1 + k0 + 32);
      f1b = *(const floatx4*)(bp1 + k0 + 36);
    }
    bf16x8 af[4], bfr[4];
#pragma unroll
    for (int i = 0; i < 4; i++) {
      af[i]  = *(const bf16x8*)(As + (wm + i * 16 + l16) * 32 + quad * 8);
      bfr[i] = *(const bf16x8*)(Bs + (wn + i * 16 + l16) * 32 + quad * 8);
    }
#pragma unroll
    for (int i = 0; i < 4; i++)
#pragma unroll
      for (int j = 0; j < 4; j++)
        acc[i][j] = __builtin_amdgcn_mfma_f32_16x16x32_bf16(af[i], bfr[j], acc[i][j], 0, 0, 0);
    __syncthreads();
  }

#pragma unroll
  for (int i = 0; i < 4; i++) {
#pragma unroll
    for (int r = 0; r < 4; r++) {
      const int m = wm + i * 16 + quad * 4 + r;
      if (m0 + m < count) {
        float* op = yp + ((size_t)ks * (TT * 2) + base + m0 + m) * HH + n0 + wn + l16;
#pragma unroll
        for (int j = 0; j < 4; j++) op[j * 16] = acc[i][j][r];
      }
    }
  }
}

// ---------------- combine: out[t] = sum_k w_k * sum_ks yp[ks][slot_k] -------
__global__ __launch_bounds__(256) void k_combine(
    const float* __restrict__ yp, const int* __restrict__ inv_slot,
    const float* __restrict__ sel_w, float* __restrict__ out) {
  const int t = blockIdx.x;
  const int tid = threadIdx.x;
  const int s0 = inv_slot[2 * t];
  const int s1 = inv_slot[2 * t + 1];
  const float w0 = sel_w[2 * t];
  const float w1 = sel_w[2 * t + 1];
  floatx4 a = {0.f, 0.f, 0.f, 0.f};
  floatx4 b = {0.f, 0.f, 0.f, 0.f};
#pragma unroll
  for (int ks = 0; ks < KS; ks++) {
    a += ((const floatx4*)(yp + ((size_t)ks * (TT * 2) + s0) * HH))[tid];
    b += ((const floatx4*)(yp + ((size_t)ks * (TT * 2) + s1) * HH))[tid];
  }
  floatx4 v = w0 * a + w1 * b;
  ((floatx4*)(out + (size_t)t * HH))[tid] = v;
}

// ---------------- launch ----------------------------------------------------
extern "C" void kernel_launch(void* const* d_in, const int* in_sizes, int n_in,
                              void* d_out, int out_size, void* d_ws, size_t ws_size,
                              hipStream_t stream) {
  const float* x  = (const float*)d_in[0];
  const float* gw = (const float*)d_in[1];
  const float* w1 = (const float*)d_in[2];
  const float* w2 = (const float*)d_in[3];
  float* out = (float*)d_out;

  char* ws = (char*)d_ws;
  size_t off = 0;
  auto take = [&](size_t n) -> char* {
    char* p = ws + off;
    off += (n + 255) & ~(size_t)255;
    return p;
  };
  unsigned short* xb  = (unsigned short*)take((size_t)TT * HH * 2);
  unsigned short* hid = (unsigned short*)take((size_t)TT * 2 * II * 2);
  float* yp = (float*)take((size_t)KS * (TT * 2) * HH * 4);
  int*   counts    = (int*)take(EE * 4);
  int*   bases     = (int*)take(EE * 4);
  int*   row_token = (int*)take((size_t)TT * 2 * 4);
  float* row_w     = (float*)take((size_t)TT * 2 * 4);
  int*   sel_e     = (int*)take((size_t)TT * 2 * 4);
  float* sel_w     = (float*)take((size_t)TT * 2 * 4);
  int*   inv_slot  = (int*)take((size_t)TT * 2 * 4);
  if (off > ws_size) return;  // workspace too small — fail loudly via absmax

  hipMemsetAsync(counts, 0, EE * 4, stream);

  k_gating<<<TT, 256, 0, stream>>>(x, gw, xb, sel_e, sel_w, counts);
  k_fill<<<1, 256, 0, stream>>>(counts, sel_e, sel_w, bases, row_token, row_w, inv_slot);
  k_gemm1<<<dim3(II / 128, 16, EE), 256, 0, stream>>>(xb, w1, hid, counts, bases, row_token);
  k_gemm2<<<dim3(8 * KS, 16, EE), 256, 0, stream>>>(hid, w2, yp, counts, bases);
  k_combine<<<TT, 256, 0, stream>>>(yp, inv_slot, sel_w, out);
}